// Round 4
// baseline (763.852 us; speedup 1.0000x reference)
//
#include <hip/hip_runtime.h>
#include <hip/hip_bf16.h>

typedef __attribute__((ext_vector_type(8))) short short8;   // 8 bf16 = 4 VGPRs (MFMA A/B frag)
typedef __attribute__((ext_vector_type(4))) float f32x4;    // MFMA C/D frag

#define MFMA(a, b, c) __builtin_amdgcn_mfma_f32_16x16x32_bf16((a), (b), (c), 0, 0, 0)

__device__ __forceinline__ unsigned short f2bf(float f) {
    unsigned int u = __float_as_uint(f);
    u += 0x7fffu + ((u >> 16) & 1u);          // round-to-nearest-even
    return (unsigned short)(u >> 16);
}

// 16-lane sum via DPP row_ror (VALU-only, no ds_swizzle).
template<int CTRL>
__device__ __forceinline__ float dpp_addf(float v) {
    int t = __builtin_amdgcn_update_dpp(0, __float_as_int(v), CTRL, 0xF, 0xF, true);
    return v + __int_as_float(t);
}
__device__ __forceinline__ float rowsum16(float v) {
    v = dpp_addf<0x121>(v);   // row_ror:1
    v = dpp_addf<0x122>(v);   // row_ror:2
    v = dpp_addf<0x124>(v);   // row_ror:4
    v = dpp_addf<0x128>(v);   // row_ror:8
    return v;
}

// gelu tanh-form: x*E/(E+1), E=exp(x*(1.59576912+0.07135533x^2)); |err| <~3e-4.
__device__ __forceinline__ float gelu_fast(float x) {
    x = __builtin_amdgcn_fmed3f(x, -8.0f, 8.0f);
    float a = x * __builtin_fmaf(x * x, 0.07135533f, 1.59576912f);
    float E = __expf(a);
    float r = __builtin_amdgcn_rcpf(E + 1.0f);
    return x * E * r;
}

// B fragment from row-major [K][ldn] fp32 weight: r[u] = W[k0+u][n].
__device__ __forceinline__ short8 load_bfrag(const float* __restrict__ w, int k0, int n, int ldn) {
    short8 r;
#pragma unroll
    for (int u = 0; u < 8; ++u)
        r[u] = (short)f2bf(w[(k0 + u) * ldn + n]);
    return r;
}

struct SmemEdge {
    unsigned short sA[2][64 * 136];  // double-buffered gathered edge features (bf16)
    float rstat[64 * 8];             // (s,ss) per row per col-wave
    float spL[64 * 4];
};
template<int N1P>
struct SmemMlp {
    unsigned short sS[64 * N1P];     // union: A [64][K+8] then gelu(h) [64][N1P]
    float rstat[64 * 8];
};
union SmemU {
    SmemEdge e;
    SmemMlp<136> a;   // head A: N1=128
    SmemMlp<264> b;   // head B: N1=256
};

// ---------------------------------------------------------------------------
// Edge head: ef=[x[row],x[col]] (K=128); h=LN(ef@W1+b1)*g+be; out=gelu(h)@w2+b2
// Tile 64 edges x 256 cols; 4 waves each own a 64-col strip (full LN spans 4 waves).
// W1^T frags persistent in regs; sA double-buffered; 2 barriers/tile.
// ---------------------------------------------------------------------------
__device__ void edge_role(SmemEdge& sm, const float* __restrict__ x, const int* __restrict__ ei,
                          const float* __restrict__ w1, const float* __restrict__ b1,
                          const float* __restrict__ g, const float* __restrict__ be,
                          const float* __restrict__ w2, const float* __restrict__ b2,
                          float* __restrict__ out, int E, int bid, int nblocks) {
    constexpr int KP = 136;
    const int tid = threadIdx.x;
    const int cw = tid >> 6, lane = tid & 63;       // 4 col-waves
    const int l15 = lane & 15, quad = lane >> 4;

    short8 breg[4][4];
#pragma unroll
    for (int j = 0; j < 4; ++j)
#pragma unroll
        for (int kk = 0; kk < 4; ++kk)
            breg[j][kk] = load_bfrag(w1, kk * 32 + quad * 8, cw * 64 + 16 * j + l15, 256);

    float b1v[4], gv[4], bev[4], w2v[4];
#pragma unroll
    for (int j = 0; j < 4; ++j) {
        int c = cw * 64 + 16 * j + l15;
        b1v[j] = b1[c]; gv[j] = g[c]; bev[j] = be[c]; w2v[j] = w2[c];
    }
    const float b2v = b2[0];

    const int ntiles = (E + 63) >> 6;
    const int eLoc = tid >> 2, p = tid & 3;         // 4 threads per edge, 32 floats each

    float4 pf[8];
    auto issue = [&](int t) {                       // prefetch gather for tile t into regs
        int e = t * 64 + eLoc; if (e >= E) e = E - 1;
        int idx = ei[(p >> 1) * E + e];             // p<2: row node, p>=2: col node
        const float4* src = (const float4*)(x + (long)idx * 64 + (p & 1) * 32);
#pragma unroll
        for (int u = 0; u < 8; ++u) pf[u] = src[u];
    };
    auto stage = [&](int buf) {                     // regs -> sA[buf] (bf16)
        unsigned short* dst = &sm.sA[buf][eLoc * KP + p * 32];
#pragma unroll
        for (int u = 0; u < 8; ++u) {
            ushort4 h;
            h.x = f2bf(pf[u].x); h.y = f2bf(pf[u].y);
            h.z = f2bf(pf[u].z); h.w = f2bf(pf[u].w);
            *(ushort4*)(dst + 4 * u) = h;
        }
    };

    int t = bid;
    if (t >= ntiles) { return; }
    issue(t); stage(0);
    if (t + nblocks < ntiles) issue(t + nblocks);
    __syncthreads();                                // B0: sA[0] ready
    int cur = 0;

    for (; t < ntiles; t += nblocks) {
        f32x4 acc[4][4];
#pragma unroll
        for (int i = 0; i < 4; ++i)
#pragma unroll
            for (int j = 0; j < 4; ++j)
                acc[i][j] = (f32x4){0.f, 0.f, 0.f, 0.f};

#pragma unroll
        for (int kk = 0; kk < 4; ++kk) {
            short8 a[4];
#pragma unroll
            for (int i = 0; i < 4; ++i)
                a[i] = *(const short8*)&sm.sA[cur][(16 * i + l15) * KP + kk * 32 + quad * 8];
#pragma unroll
            for (int i = 0; i < 4; ++i)
#pragma unroll
                for (int j = 0; j < 4; ++j)
                    acc[i][j] = MFMA(a[i], breg[j][kk], acc[i][j]);
        }

        // stage NEXT tile into the other buffer (no barrier here; B2 fences it)
        if (t + nblocks < ntiles) {
            stage(cur ^ 1);
            if (t + 2 * nblocks < ntiles) issue(t + 2 * nblocks);
        }

        // pass A: v = acc + b1 in place; per-row (s,ss) partials via DPP
#pragma unroll
        for (int i = 0; i < 4; ++i)
#pragma unroll
            for (int r = 0; r < 4; ++r) {
                float v0 = acc[i][0][r] + b1v[0];
                float v1 = acc[i][1][r] + b1v[1];
                float v2 = acc[i][2][r] + b1v[2];
                float v3 = acc[i][3][r] + b1v[3];
                acc[i][0][r] = v0; acc[i][1][r] = v1; acc[i][2][r] = v2; acc[i][3][r] = v3;
                float s  = (v0 + v1) + (v2 + v3);
                float ss = __builtin_fmaf(v0, v0, __builtin_fmaf(v1, v1,
                           __builtin_fmaf(v2, v2, v3 * v3)));
                s = rowsum16(s); ss = rowsum16(ss);
                if (l15 == 0) {
                    int row = 16 * i + quad * 4 + r;       // C/D: row = quad*4+reg
                    *(float2*)&sm.rstat[row * 8 + cw * 2] = make_float2(s, ss);
                }
            }
        __syncthreads();                            // B2: rstat ready + next-tile sA staged

#pragma unroll
        for (int i = 0; i < 4; ++i)
#pragma unroll
            for (int r = 0; r < 4; ++r) {
                int row = 16 * i + quad * 4 + r;
                const float4* st = (const float4*)&sm.rstat[row * 8];
                float4 q0 = st[0], q1 = st[1];
                float s  = (q0.x + q0.z) + (q1.x + q1.z);
                float ss = (q0.y + q0.w) + (q1.y + q1.w);
                float mean = s * (1.f / 256.f);
                float var  = __builtin_fmaf(ss, 1.f / 256.f, -mean * mean);
                float rstd = __builtin_amdgcn_rsqf(var + 1e-5f);
                float nm = -mean * rstd;
                float spp = 0.f;
#pragma unroll
                for (int j = 0; j < 4; ++j) {
                    float tt = __builtin_fmaf(acc[i][j][r], rstd, nm);
                    float xn = __builtin_fmaf(tt, gv[j], bev[j]);
                    spp = __builtin_fmaf(gelu_fast(xn), w2v[j], spp);
                }
                spp = rowsum16(spp);
                if (l15 == 0) sm.spL[row * 4 + cw] = spp;
            }
        __syncthreads();                            // B3: spL ready (also fences rstat reuse)

        int e = t * 64 + tid;
        if (tid < 64 && e < E)
            out[e] = sm.spL[tid*4+0] + sm.spL[tid*4+1] + sm.spL[tid*4+2] + sm.spL[tid*4+3] + b2v;
        cur ^= 1;
    }
}

// ---------------------------------------------------------------------------
// MLP heads: out = gelu(LN(x@W1+b1)*g+be) @ W2 + b2.  4 waves, 64-row tiles.
// ---------------------------------------------------------------------------
template<int K, int N1, int N2>
__device__ void mlp_role(SmemMlp<N1 + 8>& sm, const float* __restrict__ x,
                         const float* __restrict__ w1, const float* __restrict__ b1,
                         const float* __restrict__ g, const float* __restrict__ be,
                         const float* __restrict__ w2, const float* __restrict__ b2,
                         float* __restrict__ out, int Nrows, int bid, int nblocks) {
    constexpr int KP = K + 8, N1P = N1 + 8;
    constexpr int JT1 = N1 / 64;
    constexpr int JT2 = (N2 >= 64) ? N2 / 64 : 1;
    constexpr int CPW1 = N1 / 4, CPW2 = N2 / 4;
    constexpr int KK1 = K / 32, KK2 = N1 / 32;

    const int tid = threadIdx.x;
    const int wave = tid >> 6, lane = tid & 63;
    const int l15 = lane & 15, quad = lane >> 4;

    short8 breg1[JT1][KK1];
#pragma unroll
    for (int j = 0; j < JT1; ++j)
#pragma unroll
        for (int kk = 0; kk < KK1; ++kk)
            breg1[j][kk] = load_bfrag(w1, kk * 32 + quad * 8, CPW1 * wave + 16 * j + l15, N1);

    float b1v[JT1], gv[JT1], bev[JT1];
#pragma unroll
    for (int j = 0; j < JT1; ++j) {
        int c = CPW1 * wave + 16 * j + l15;
        b1v[j] = b1[c]; gv[j] = g[c]; bev[j] = be[c];
    }
    float b2v[JT2];
#pragma unroll
    for (int j = 0; j < JT2; ++j) b2v[j] = b2[CPW2 * wave + 16 * j + l15];

    const int ntiles = (Nrows + 63) >> 6;
    const int m0 = tid >> 2, p = tid & 3;

    for (int t = bid; t < ntiles; t += nblocks) {
        const int r0 = t << 6;
        __syncthreads();                       // B0: prev GEMM2 reads of sS done
        {
            int rowg = r0 + m0; if (rowg >= Nrows) rowg = Nrows - 1;
            const float4* src = (const float4*)(x + (long)rowg * K + p * (K / 4));
            unsigned short* dst = &sm.sS[m0 * KP + p * (K / 4)];
#pragma unroll
            for (int u = 0; u < K / 16; ++u) {
                float4 f = src[u];
                ushort4 h; h.x = f2bf(f.x); h.y = f2bf(f.y); h.z = f2bf(f.z); h.w = f2bf(f.w);
                *(ushort4*)(dst + 4 * u) = h;
            }
        }
        __syncthreads();                       // B1: A ready

        f32x4 acc1[4][JT1];
#pragma unroll
        for (int i = 0; i < 4; ++i)
#pragma unroll
            for (int j = 0; j < JT1; ++j)
                acc1[i][j] = (f32x4){0.f, 0.f, 0.f, 0.f};

#pragma unroll
        for (int kk = 0; kk < KK1; ++kk) {
            short8 a[4];
#pragma unroll
            for (int i = 0; i < 4; ++i)
                a[i] = *(const short8*)&sm.sS[(16 * i + l15) * KP + kk * 32 + quad * 8];
#pragma unroll
            for (int i = 0; i < 4; ++i)
#pragma unroll
                for (int j = 0; j < JT1; ++j)
                    acc1[i][j] = MFMA(a[i], breg1[j][kk], acc1[i][j]);
        }

#pragma unroll
        for (int i = 0; i < 4; ++i)
#pragma unroll
            for (int r = 0; r < 4; ++r) {
                float s = 0.f, ss = 0.f;
#pragma unroll
                for (int j = 0; j < JT1; ++j) {
                    float v = acc1[i][j][r] + b1v[j];
                    acc1[i][j][r] = v;
                    s += v; ss = __builtin_fmaf(v, v, ss);
                }
                s = rowsum16(s); ss = rowsum16(ss);
                if (l15 == 0) {
                    int row = 16 * i + quad * 4 + r;
                    *(float2*)&sm.rstat[row * 8 + wave * 2] = make_float2(s, ss);
                }
            }
        __syncthreads();                       // B2: partials ready (GEMM1 sS reads done)

#pragma unroll
        for (int i = 0; i < 4; ++i)
#pragma unroll
            for (int r = 0; r < 4; ++r) {
                int row = 16 * i + quad * 4 + r;
                const float4* st = (const float4*)&sm.rstat[row * 8];
                float4 q0 = st[0], q1 = st[1];
                float s  = (q0.x + q0.z) + (q1.x + q1.z);
                float ss = (q0.y + q0.w) + (q1.y + q1.w);
                float mean = s * (1.f / (float)N1);
                float var  = __builtin_fmaf(ss, 1.f / (float)N1, -mean * mean);
                float rstd = __builtin_amdgcn_rsqf(var + 1e-5f);
                float nm = -mean * rstd;
#pragma unroll
                for (int j = 0; j < JT1; ++j) {
                    float tt = __builtin_fmaf(acc1[i][j][r], rstd, nm);
                    float xn = __builtin_fmaf(tt, gv[j], bev[j]);
                    sm.sS[row * N1P + CPW1 * wave + 16 * j + l15] = f2bf(gelu_fast(xn));
                }
            }
        __syncthreads();                       // B3: gelu(h) ready in A-layout

        short8 breg2[JT2][KK2];
#pragma unroll
        for (int j = 0; j < JT2; ++j)
#pragma unroll
            for (int kk = 0; kk < KK2; ++kk)
                breg2[j][kk] = load_bfrag(w2, kk * 32 + quad * 8, CPW2 * wave + 16 * j + l15, N2);

        f32x4 acc2[4][JT2];
#pragma unroll
        for (int i = 0; i < 4; ++i)
#pragma unroll
            for (int j = 0; j < JT2; ++j)
                acc2[i][j] = (f32x4){0.f, 0.f, 0.f, 0.f};

#pragma unroll
        for (int kk = 0; kk < KK2; ++kk) {
            short8 a[4];
#pragma unroll
            for (int i = 0; i < 4; ++i)
                a[i] = *(const short8*)&sm.sS[(16 * i + l15) * N1P + kk * 32 + quad * 8];
#pragma unroll
            for (int i = 0; i < 4; ++i)
#pragma unroll
                for (int j = 0; j < JT2; ++j)
                    acc2[i][j] = MFMA(a[i], breg2[j][kk], acc2[i][j]);
        }

#pragma unroll
        for (int i = 0; i < 4; ++i)
#pragma unroll
            for (int r = 0; r < 4; ++r) {
                int rowg = r0 + 16 * i + quad * 4 + r;
                if (rowg < Nrows) {
#pragma unroll
                    for (int j = 0; j < JT2; ++j)
                        out[(long)rowg * N2 + CPW2 * wave + 16 * j + l15] = acc2[i][j][r] + b2v[j];
                }
            }
    }
}

// Merged kernel, 256 threads everywhere: MLP blocks (0..511) dispatch first.
__global__ __launch_bounds__(256, 4)
void fused_all(const float* __restrict__ x, const int* __restrict__ ei,
               const float* __restrict__ sp_w1, const float* __restrict__ sp_b1,
               const float* __restrict__ sp_g, const float* __restrict__ sp_be,
               const float* __restrict__ sp_w2, const float* __restrict__ sp_b2,
               const float* __restrict__ fr_w1, const float* __restrict__ fr_b1,
               const float* __restrict__ fr_g, const float* __restrict__ fr_be,
               const float* __restrict__ fr_w2, const float* __restrict__ fr_b2,
               const float* __restrict__ ph_w1, const float* __restrict__ ph_b1,
               const float* __restrict__ ph_g, const float* __restrict__ ph_be,
               const float* __restrict__ ph_w2, const float* __restrict__ ph_b2,
               float* __restrict__ out_sp, float* __restrict__ out_rec,
               float* __restrict__ out_proj, int N, int E) {
    __shared__ SmemU sm;
    const int b = blockIdx.x;
    if (b < 256) {
        mlp_role<64, 128, 64>(sm.a, x, fr_w1, fr_b1, fr_g, fr_be, fr_w2, fr_b2,
                              out_rec, N, b, 256);
    } else if (b < 512) {
        mlp_role<64, 256, 128>(sm.b, x, ph_w1, ph_b1, ph_g, ph_be, ph_w2, ph_b2,
                               out_proj, N, b - 256, 256);
    } else {
        edge_role(sm.e, x, ei, sp_w1, sp_b1, sp_g, sp_be, sp_w2, sp_b2,
                  out_sp, E, b - 512, 1024);
    }
}

extern "C" void kernel_launch(void* const* d_in, const int* in_sizes, int n_in,
                              void* d_out, int out_size, void* d_ws, size_t ws_size,
                              hipStream_t stream) {
    const float* x     = (const float*)d_in[0];
    const int*   ei    = (const int*)d_in[1];

    const int N = in_sizes[0] / 64;
    const int E = in_sizes[1] / 2;

    float* out_sp   = (float*)d_out;
    float* out_rec  = out_sp + E;
    float* out_proj = out_rec + (size_t)N * 64;

    fused_all<<<dim3(1536), dim3(256), 0, stream>>>(
        x, ei,
        (const float*)d_in[2],  (const float*)d_in[3],  (const float*)d_in[4],
        (const float*)d_in[5],  (const float*)d_in[6],  (const float*)d_in[7],
        (const float*)d_in[8],  (const float*)d_in[9],  (const float*)d_in[10],
        (const float*)d_in[11], (const float*)d_in[12], (const float*)d_in[13],
        (const float*)d_in[14], (const float*)d_in[15], (const float*)d_in[16],
        (const float*)d_in[17], (const float*)d_in[18], (const float*)d_in[19],
        out_sp, out_rec, out_proj, N, E);
}

// Round 5
// 564.266 us; speedup vs baseline: 1.3537x; 1.3537x over previous
//
#include <hip/hip_runtime.h>
#include <hip/hip_bf16.h>

typedef __attribute__((ext_vector_type(8))) short short8;   // 8 bf16 = 4 VGPRs (MFMA A/B frag)
typedef __attribute__((ext_vector_type(4))) float f32x4;    // MFMA C/D frag

#define MFMA(a, b, c) __builtin_amdgcn_mfma_f32_16x16x32_bf16((a), (b), (c), 0, 0, 0)

__device__ __forceinline__ unsigned short f2bf(float f) {
    unsigned int u = __float_as_uint(f);
    u += 0x7fffu + ((u >> 16) & 1u);          // round-to-nearest-even
    return (unsigned short)(u >> 16);
}

// 16-lane sum via DPP row_ror (VALU-only, no ds_swizzle).
template<int CTRL>
__device__ __forceinline__ float dpp_addf(float v) {
    int t = __builtin_amdgcn_update_dpp(0, __float_as_int(v), CTRL, 0xF, 0xF, true);
    return v + __int_as_float(t);
}
__device__ __forceinline__ float rowsum16(float v) {
    v = dpp_addf<0x121>(v);   // row_ror:1
    v = dpp_addf<0x122>(v);   // row_ror:2
    v = dpp_addf<0x124>(v);   // row_ror:4
    v = dpp_addf<0x128>(v);   // row_ror:8
    return v;
}

// gelu tanh-form: x*E/(E+1), E=exp(x*(1.59576912+0.07135533x^2)); |err| <~3e-4.
__device__ __forceinline__ float gelu_fast(float x) {
    x = __builtin_amdgcn_fmed3f(x, -8.0f, 8.0f);
    float a = x * __builtin_fmaf(x * x, 0.07135533f, 1.59576912f);
    float E = __expf(a);
    float r = __builtin_amdgcn_rcpf(E + 1.0f);
    return x * E * r;
}

// B fragment from row-major [K][ldn] fp32 weight: r[u] = W[k0+u][n].
__device__ __forceinline__ short8 load_bfrag(const float* __restrict__ w, int k0, int n, int ldn) {
    short8 r;
#pragma unroll
    for (int u = 0; u < 8; ++u)
        r[u] = (short)f2bf(w[(k0 + u) * ldn + n]);
    return r;
}

struct SmemEdge {
    unsigned short sA[2][64 * 136];  // double-buffered gathered edge features (bf16), 34.8 KB
    float rstat[64 * 16];            // (s,ss) float2 per row per col-wave (8 waves)
    float spL[64 * 8];               // per-row partial dots (8 waves)
};
template<int N1P>
struct SmemMlp {
    unsigned short sS[64 * N1P];     // union: A [64][K+8] then gelu(h) [64][N1P]
    float rstat[64 * 16];
};
union SmemU {
    SmemEdge e;          // 40.9 KB
    SmemMlp<136> a;      // head A: N1=128 -> 21.5 KB
    SmemMlp<264> b;      // head B: N1=256 -> 37.9 KB
};

// ---------------------------------------------------------------------------
// Edge head: ef=[x[row],x[col]] (K=128); h=LN(ef@W1+b1)*g+be; out=gelu(h)@w2+b2
// Tile 64 edges x 256 cols; 8 col-waves of 32 cols (LN spans 8 waves).
// Per wave: acc[4][2]=32 AGPR, breg[2][4]=32 VGPR -> fits 128-reg budget.
// sA double-buffered; 2 barriers/tile.
// ---------------------------------------------------------------------------
__device__ void edge_role(SmemEdge& sm, const float* __restrict__ x, const int* __restrict__ ei,
                          const float* __restrict__ w1, const float* __restrict__ b1,
                          const float* __restrict__ g, const float* __restrict__ be,
                          const float* __restrict__ w2, const float* __restrict__ b2,
                          float* __restrict__ out, int E, int bid, int nblocks) {
    constexpr int KP = 136;                          // 272B row stride -> 2-way bank alias (free)
    const int tid = threadIdx.x;
    const int cw = tid >> 6, lane = tid & 63;        // 8 col-waves
    const int l15 = lane & 15, quad = lane >> 4;

    short8 breg[2][4];
#pragma unroll
    for (int j = 0; j < 2; ++j)
#pragma unroll
        for (int kk = 0; kk < 4; ++kk)
            breg[j][kk] = load_bfrag(w1, kk * 32 + quad * 8, cw * 32 + 16 * j + l15, 256);

    float b1v[2], gv[2], bev[2], w2v[2];
#pragma unroll
    for (int j = 0; j < 2; ++j) {
        int c = cw * 32 + 16 * j + l15;
        b1v[j] = b1[c]; gv[j] = g[c]; bev[j] = be[c]; w2v[j] = w2[c];
    }
    const float b2v = b2[0];

    const int ntiles = (E + 63) >> 6;
    const int eLoc = tid >> 3, p = tid & 7;          // 8 threads per edge, 16 floats each
    const int node = p >> 2, foff = (p & 3) * 16;    // node 0 = row, 1 = col half

    float4 pf[4];
    auto issue = [&](int t) {                        // prefetch gather for tile t into regs
        int e = t * 64 + eLoc; if (e >= E) e = E - 1;
        int idx = ei[node * E + e];
        const float4* src = (const float4*)(x + (long)idx * 64 + foff);
#pragma unroll
        for (int u = 0; u < 4; ++u) pf[u] = src[u];
    };
    auto stage = [&](int buf) {                      // regs -> sA[buf] (bf16)
        unsigned short* dst = &sm.sA[buf][eLoc * KP + node * 64 + foff];
#pragma unroll
        for (int u = 0; u < 4; ++u) {
            ushort4 h;
            h.x = f2bf(pf[u].x); h.y = f2bf(pf[u].y);
            h.z = f2bf(pf[u].z); h.w = f2bf(pf[u].w);
            *(ushort4*)(dst + 4 * u) = h;
        }
    };

    int t = bid;
    if (t >= ntiles) return;                         // block-uniform
    issue(t); stage(0);
    if (t + nblocks < ntiles) issue(t + nblocks);
    __syncthreads();                                 // B0: sA[0] ready
    int cur = 0;

    for (; t < ntiles; t += nblocks) {
        f32x4 acc[4][2];
#pragma unroll
        for (int i = 0; i < 4; ++i)
#pragma unroll
            for (int j = 0; j < 2; ++j)
                acc[i][j] = (f32x4){0.f, 0.f, 0.f, 0.f};

#pragma unroll
        for (int kk = 0; kk < 4; ++kk) {
            short8 a[4];
#pragma unroll
            for (int i = 0; i < 4; ++i)
                a[i] = *(const short8*)&sm.sA[cur][(16 * i + l15) * KP + kk * 32 + quad * 8];
#pragma unroll
            for (int i = 0; i < 4; ++i)
#pragma unroll
                for (int j = 0; j < 2; ++j)
                    acc[i][j] = MFMA(a[i], breg[j][kk], acc[i][j]);
        }

        // stage NEXT tile into the other buffer (no barrier here; B2 fences it)
        if (t + nblocks < ntiles) {
            stage(cur ^ 1);
            if (t + 2 * nblocks < ntiles) issue(t + 2 * nblocks);
        }

        // pass A: v = acc + b1 in place; per-row (s,ss) partials via DPP
#pragma unroll
        for (int i = 0; i < 4; ++i)
#pragma unroll
            for (int r = 0; r < 4; ++r) {
                float v0 = acc[i][0][r] + b1v[0];
                float v1 = acc[i][1][r] + b1v[1];
                acc[i][0][r] = v0; acc[i][1][r] = v1;
                float s  = v0 + v1;
                float ss = __builtin_fmaf(v0, v0, v1 * v1);
                s = rowsum16(s); ss = rowsum16(ss);
                if (l15 == 0) {
                    int row = 16 * i + quad * 4 + r;          // C/D: row = quad*4+reg
                    *(float2*)&sm.rstat[row * 16 + cw * 2] = make_float2(s, ss);
                }
            }
        __syncthreads();                             // B2: rstat ready + next-tile sA staged

#pragma unroll
        for (int i = 0; i < 4; ++i)
#pragma unroll
            for (int r = 0; r < 4; ++r) {
                int row = 16 * i + quad * 4 + r;
                const float4* st = (const float4*)&sm.rstat[row * 16];
                float4 q0 = st[0], q1 = st[1], q2 = st[2], q3 = st[3];
                float s  = ((q0.x + q0.z) + (q1.x + q1.z)) + ((q2.x + q2.z) + (q3.x + q3.z));
                float ss = ((q0.y + q0.w) + (q1.y + q1.w)) + ((q2.y + q2.w) + (q3.y + q3.w));
                float mean = s * (1.f / 256.f);
                float var  = __builtin_fmaf(ss, 1.f / 256.f, -mean * mean);
                float rstd = __builtin_amdgcn_rsqf(var + 1e-5f);
                float nm = -mean * rstd;
                float spp = 0.f;
#pragma unroll
                for (int j = 0; j < 2; ++j) {
                    float tt = __builtin_fmaf(acc[i][j][r], rstd, nm);
                    float xn = __builtin_fmaf(tt, gv[j], bev[j]);
                    spp = __builtin_fmaf(gelu_fast(xn), w2v[j], spp);
                }
                spp = rowsum16(spp);
                if (l15 == 0) sm.spL[row * 8 + cw] = spp;
            }
        __syncthreads();                             // B3: spL ready (fences rstat reuse)

        if (tid < 64) {
            int e = t * 64 + tid;
            if (e < E) {
                const float4* sp = (const float4*)&sm.spL[tid * 8];
                float4 u0 = sp[0], u1 = sp[1];
                out[e] = ((u0.x + u0.y) + (u0.z + u0.w)) +
                         ((u1.x + u1.y) + (u1.z + u1.w)) + b2v;
            }
        }
        cur ^= 1;
    }
}

// ---------------------------------------------------------------------------
// MLP heads: out = gelu(LN(x@W1+b1)*g+be) @ W2 + b2.
// 8 col-waves over N1 (CPW1 = N1/8 cols each); GEMM2 on N2/16 waves, 16 cols each.
// All register arrays sized to fit the shared 128-reg budget.
// ---------------------------------------------------------------------------
template<int K, int N1, int N2>
__device__ void mlp_role(SmemMlp<N1 + 8>& sm, const float* __restrict__ x,
                         const float* __restrict__ w1, const float* __restrict__ b1,
                         const float* __restrict__ g, const float* __restrict__ be,
                         const float* __restrict__ w2, const float* __restrict__ b2,
                         float* __restrict__ out, int Nrows, int bid, int nblocks) {
    constexpr int KP = K + 8, N1P = N1 + 8;
    constexpr int CPW1 = N1 / 8;           // cols per wave, GEMM1 (A:16, B:32)
    constexpr int JT1 = CPW1 / 16;         // j-tiles per wave (A:1, B:2)
    constexpr int KK1 = K / 32;            // 2
    constexpr int KK2 = N1 / 32;           // A:4, B:8
    constexpr int W2W = N2 / 16;           // waves active in GEMM2 (A:4, B:8)

    const int tid = threadIdx.x;
    const int wave = tid >> 6, lane = tid & 63;
    const int l15 = lane & 15, quad = lane >> 4;

    short8 breg1[JT1][KK1];
#pragma unroll
    for (int j = 0; j < JT1; ++j)
#pragma unroll
        for (int kk = 0; kk < KK1; ++kk)
            breg1[j][kk] = load_bfrag(w1, kk * 32 + quad * 8, CPW1 * wave + 16 * j + l15, N1);

    float b1v[JT1], gv[JT1], bev[JT1];
#pragma unroll
    for (int j = 0; j < JT1; ++j) {
        int c = CPW1 * wave + 16 * j + l15;
        b1v[j] = b1[c]; gv[j] = g[c]; bev[j] = be[c];
    }

    const bool w2act = (wave < W2W);
    const int c2 = w2act ? wave * 16 + l15 : 0;
    short8 breg2[KK2];
    if (w2act) {
#pragma unroll
        for (int kk = 0; kk < KK2; ++kk)
            breg2[kk] = load_bfrag(w2, kk * 32 + quad * 8, c2, N2);
    }
    const float b2v = w2act ? b2[c2] : 0.f;

    const int ntiles = (Nrows + 63) >> 6;
    const int m0 = tid >> 3, p = tid & 3 | ((tid & 7) & ~3); // p = tid & 7
    const int pp = tid & 7;

    for (int t = bid; t < ntiles; t += nblocks) {
        const int r0 = t << 6;
        __syncthreads();                       // B0: prev GEMM2 reads of sS done
        {
            int rowg = r0 + m0; if (rowg >= Nrows) rowg = Nrows - 1;
            const float4* src = (const float4*)(x + (long)rowg * K + pp * (K / 8));
            unsigned short* dst = &sm.sS[m0 * KP + pp * (K / 8)];
#pragma unroll
            for (int u = 0; u < K / 32; ++u) {             // K/8 floats = K/32 float4s
                float4 f = src[u];
                ushort4 h; h.x = f2bf(f.x); h.y = f2bf(f.y); h.z = f2bf(f.z); h.w = f2bf(f.w);
                *(ushort4*)(dst + 4 * u) = h;
            }
        }
        __syncthreads();                       // B1: A ready

        f32x4 acc1[4][JT1];
#pragma unroll
        for (int i = 0; i < 4; ++i)
#pragma unroll
            for (int j = 0; j < JT1; ++j)
                acc1[i][j] = (f32x4){0.f, 0.f, 0.f, 0.f};

#pragma unroll
        for (int kk = 0; kk < KK1; ++kk) {
            short8 a[4];
#pragma unroll
            for (int i = 0; i < 4; ++i)
                a[i] = *(const short8*)&sm.sS[(16 * i + l15) * KP + kk * 32 + quad * 8];
#pragma unroll
            for (int i = 0; i < 4; ++i)
#pragma unroll
                for (int j = 0; j < JT1; ++j)
                    acc1[i][j] = MFMA(a[i], breg1[j][kk], acc1[i][j]);
        }

#pragma unroll
        for (int i = 0; i < 4; ++i)
#pragma unroll
            for (int r = 0; r < 4; ++r) {
                float s = 0.f, ss = 0.f;
#pragma unroll
                for (int j = 0; j < JT1; ++j) {
                    float v = acc1[i][j][r] + b1v[j];
                    acc1[i][j][r] = v;
                    s += v; ss = __builtin_fmaf(v, v, ss);
                }
                s = rowsum16(s); ss = rowsum16(ss);
                if (l15 == 0) {
                    int row = 16 * i + quad * 4 + r;
                    *(float2*)&sm.rstat[row * 16 + wave * 2] = make_float2(s, ss);
                }
            }
        __syncthreads();                       // B2: partials ready (GEMM1 sS reads done)

#pragma unroll
        for (int i = 0; i < 4; ++i)
#pragma unroll
            for (int r = 0; r < 4; ++r) {
                int row = 16 * i + quad * 4 + r;
                const float4* st = (const float4*)&sm.rstat[row * 16];
                float4 q0 = st[0], q1 = st[1], q2 = st[2], q3 = st[3];
                float s  = ((q0.x + q0.z) + (q1.x + q1.z)) + ((q2.x + q2.z) + (q3.x + q3.z));
                float ss = ((q0.y + q0.w) + (q1.y + q1.w)) + ((q2.y + q2.w) + (q3.y + q3.w));
                float mean = s * (1.f / (float)N1);
                float var  = __builtin_fmaf(ss, 1.f / (float)N1, -mean * mean);
                float rstd = __builtin_amdgcn_rsqf(var + 1e-5f);
                float nm = -mean * rstd;
#pragma unroll
                for (int j = 0; j < JT1; ++j) {
                    float tt = __builtin_fmaf(acc1[i][j][r], rstd, nm);
                    float xn = __builtin_fmaf(tt, gv[j], bev[j]);
                    sm.sS[row * N1P + CPW1 * wave + 16 * j + l15] = f2bf(gelu_fast(xn));
                }
            }
        __syncthreads();                       // B3: gelu(h) ready in A-layout

        if (w2act) {
            f32x4 acc2[4];
#pragma unroll
            for (int i = 0; i < 4; ++i) acc2[i] = (f32x4){0.f, 0.f, 0.f, 0.f};
#pragma unroll
            for (int kk = 0; kk < KK2; ++kk) {
                short8 a[4];
#pragma unroll
                for (int i = 0; i < 4; ++i)
                    a[i] = *(const short8*)&sm.sS[(16 * i + l15) * N1P + kk * 32 + quad * 8];
#pragma unroll
                for (int i = 0; i < 4; ++i)
                    acc2[i] = MFMA(a[i], breg2[kk], acc2[i]);
            }
#pragma unroll
            for (int i = 0; i < 4; ++i)
#pragma unroll
                for (int r = 0; r < 4; ++r) {
                    int rowg = r0 + 16 * i + quad * 4 + r;
                    if (rowg < Nrows)
                        out[(long)rowg * N2 + c2] = acc2[i][r] + b2v;
                }
        }
    }
}

// Merged kernel, 512 threads: MLP blocks (0..255) dispatch first, edge behind.
__global__ __launch_bounds__(512, 4)
void fused_all(const float* __restrict__ x, const int* __restrict__ ei,
               const float* __restrict__ sp_w1, const float* __restrict__ sp_b1,
               const float* __restrict__ sp_g, const float* __restrict__ sp_be,
               const float* __restrict__ sp_w2, const float* __restrict__ sp_b2,
               const float* __restrict__ fr_w1, const float* __restrict__ fr_b1,
               const float* __restrict__ fr_g, const float* __restrict__ fr_be,
               const float* __restrict__ fr_w2, const float* __restrict__ fr_b2,
               const float* __restrict__ ph_w1, const float* __restrict__ ph_b1,
               const float* __restrict__ ph_g, const float* __restrict__ ph_be,
               const float* __restrict__ ph_w2, const float* __restrict__ ph_b2,
               float* __restrict__ out_sp, float* __restrict__ out_rec,
               float* __restrict__ out_proj, int N, int E) {
    __shared__ SmemU sm;
    const int b = blockIdx.x;
    if (b < 128) {
        mlp_role<64, 128, 64>(sm.a, x, fr_w1, fr_b1, fr_g, fr_be, fr_w2, fr_b2,
                              out_rec, N, b, 128);
    } else if (b < 256) {
        mlp_role<64, 256, 128>(sm.b, x, ph_w1, ph_b1, ph_g, ph_be, ph_w2, ph_b2,
                               out_proj, N, b - 128, 128);
    } else {
        edge_role(sm.e, x, ei, sp_w1, sp_b1, sp_g, sp_be, sp_w2, sp_b2,
                  out_sp, E, b - 256, 1024);
    }
}

extern "C" void kernel_launch(void* const* d_in, const int* in_sizes, int n_in,
                              void* d_out, int out_size, void* d_ws, size_t ws_size,
                              hipStream_t stream) {
    const float* x     = (const float*)d_in[0];
    const int*   ei    = (const int*)d_in[1];

    const int N = in_sizes[0] / 64;
    const int E = in_sizes[1] / 2;

    float* out_sp   = (float*)d_out;
    float* out_rec  = out_sp + E;
    float* out_proj = out_rec + (size_t)N * 64;

    fused_all<<<dim3(1280), dim3(512), 0, stream>>>(
        x, ei,
        (const float*)d_in[2],  (const float*)d_in[3],  (const float*)d_in[4],
        (const float*)d_in[5],  (const float*)d_in[6],  (const float*)d_in[7],
        (const float*)d_in[8],  (const float*)d_in[9],  (const float*)d_in[10],
        (const float*)d_in[11], (const float*)d_in[12], (const float*)d_in[13],
        (const float*)d_in[14], (const float*)d_in[15], (const float*)d_in[16],
        (const float*)d_in[17], (const float*)d_in[18], (const float*)d_in[19],
        out_sp, out_rec, out_proj, N, E);
}

// Round 6
// 406.536 us; speedup vs baseline: 1.8789x; 1.3880x over previous
//
#include <hip/hip_runtime.h>
#include <hip/hip_bf16.h>

typedef __attribute__((ext_vector_type(8))) short short8;   // 8 bf16 = 4 VGPRs (MFMA A/B frag)
typedef __attribute__((ext_vector_type(4))) float f32x4;    // MFMA C/D frag

#define MFMA(a, b, c) __builtin_amdgcn_mfma_f32_16x16x32_bf16((a), (b), (c), 0, 0, 0)

__device__ __forceinline__ unsigned short f2bf(float f) {
    unsigned int u = __float_as_uint(f);
    u += 0x7fffu + ((u >> 16) & 1u);          // round-to-nearest-even
    return (unsigned short)(u >> 16);
}

// 16-lane sum via DPP row_ror (VALU-only, no ds_swizzle).
template<int CTRL>
__device__ __forceinline__ float dpp_addf(float v) {
    int t = __builtin_amdgcn_update_dpp(0, __float_as_int(v), CTRL, 0xF, 0xF, true);
    return v + __int_as_float(t);
}
__device__ __forceinline__ float rowsum16(float v) {
    v = dpp_addf<0x121>(v);   // row_ror:1
    v = dpp_addf<0x122>(v);   // row_ror:2
    v = dpp_addf<0x124>(v);   // row_ror:4
    v = dpp_addf<0x128>(v);   // row_ror:8
    return v;
}

// gelu tanh-form: x*E/(E+1), E=exp(x*(1.59576912+0.07135533x^2)); |err| <~3e-4.
__device__ __forceinline__ float gelu_fast(float x) {
    x = __builtin_amdgcn_fmed3f(x, -8.0f, 8.0f);
    float a = x * __builtin_fmaf(x * x, 0.07135533f, 1.59576912f);
    float E = __expf(a);
    float r = __builtin_amdgcn_rcpf(E + 1.0f);
    return x * E * r;
}

// B fragment from row-major [K][ldn] fp32 weight: r[u] = W[k0+u][n].
__device__ __forceinline__ short8 load_bfrag(const float* __restrict__ w, int k0, int n, int ldn) {
    short8 r;
#pragma unroll
    for (int u = 0; u < 8; ++u)
        r[u] = (short)f2bf(w[(k0 + u) * ldn + n]);
    return r;
}

struct SmemEdge {
    unsigned short sA[2][32 * 136];  // double-buffered gathered edge features (bf16), 17.4 KB
    float rstat[32 * 8];             // (s,ss) float2 per row per wave (4 waves)
    float spL[32 * 4];
};
template<int N1P>
struct SmemMlp {
    unsigned short sS[64 * N1P];     // union: A [64][K+8] then gelu(h) [64][N1P]
    float rstat[64 * 8];
};
union SmemU {
    SmemEdge e;          // ~19 KB
    SmemMlp<136> a;      // head A: N1=128 -> ~19.4 KB
    SmemMlp<264> b;      // head B: N1=256 -> ~35.8 KB
};

// ---------------------------------------------------------------------------
// Edge head: ef=[x[row],x[col]] (K=128); h=LN(ef@W1+b1)*g+be; out=gelu(h)@w2+b2
// Tile 32 edges x 256 cols; 4 waves of 64 cols (LN spans the 4 waves in-block).
// Regs/wave: breg 64 + acc 32 (AGPR) + pf 16 + params ~17 -> fits 170-reg cap (3 waves/EU).
// sA double-buffered; 2 barriers/tile.
// ---------------------------------------------------------------------------
__device__ void edge_role(SmemEdge& sm, const float* __restrict__ x, const int* __restrict__ ei,
                          const float* __restrict__ w1, const float* __restrict__ b1,
                          const float* __restrict__ g, const float* __restrict__ be,
                          const float* __restrict__ w2, const float* __restrict__ b2,
                          float* __restrict__ out, int E, int bid, int nblocks) {
    constexpr int KP = 136;                          // 272B row stride -> 2-way alias (free)
    const int tid = threadIdx.x;
    const int cw = tid >> 6, lane = tid & 63;        // 4 col-waves
    const int l15 = lane & 15, quad = lane >> 4;

    short8 breg[4][4];
#pragma unroll
    for (int j = 0; j < 4; ++j)
#pragma unroll
        for (int kk = 0; kk < 4; ++kk)
            breg[j][kk] = load_bfrag(w1, kk * 32 + quad * 8, cw * 64 + 16 * j + l15, 256);

    float b1v[4], gv[4], bev[4], w2v[4];
#pragma unroll
    for (int j = 0; j < 4; ++j) {
        int c = cw * 64 + 16 * j + l15;
        b1v[j] = b1[c]; gv[j] = g[c]; bev[j] = be[c]; w2v[j] = w2[c];
    }
    const float b2v = b2[0];

    const int ntiles = (E + 31) >> 5;
    const int eLoc = tid >> 3, p = tid & 7;          // 8 threads per edge, 16 floats each
    const int node = p >> 2, foff = (p & 3) * 16;    // node 0 = row-half, 1 = col-half

    float4 pf[4];
    auto issue = [&](int t) {                        // prefetch gather for tile t into regs
        int e = t * 32 + eLoc; if (e >= E) e = E - 1;
        int idx = ei[node * E + e];
        const float4* src = (const float4*)(x + (long)idx * 64 + foff);
#pragma unroll
        for (int u = 0; u < 4; ++u) pf[u] = src[u];
    };
    auto stage = [&](int buf) {                      // regs -> sA[buf] (bf16)
        unsigned short* dst = &sm.sA[buf][eLoc * KP + node * 64 + foff];
#pragma unroll
        for (int u = 0; u < 4; ++u) {
            ushort4 h;
            h.x = f2bf(pf[u].x); h.y = f2bf(pf[u].y);
            h.z = f2bf(pf[u].z); h.w = f2bf(pf[u].w);
            *(ushort4*)(dst + 4 * u) = h;
        }
    };

    int t = bid;
    if (t >= ntiles) return;                         // block-uniform
    issue(t); stage(0);
    if (t + nblocks < ntiles) issue(t + nblocks);
    __syncthreads();                                 // B0: sA[0] ready
    int cur = 0;

    for (; t < ntiles; t += nblocks) {
        f32x4 acc[2][4];
#pragma unroll
        for (int i = 0; i < 2; ++i)
#pragma unroll
            for (int j = 0; j < 4; ++j)
                acc[i][j] = (f32x4){0.f, 0.f, 0.f, 0.f};

#pragma unroll
        for (int kk = 0; kk < 4; ++kk) {
            short8 a[2];
#pragma unroll
            for (int i = 0; i < 2; ++i)
                a[i] = *(const short8*)&sm.sA[cur][(16 * i + l15) * KP + kk * 32 + quad * 8];
#pragma unroll
            for (int i = 0; i < 2; ++i)
#pragma unroll
                for (int j = 0; j < 4; ++j)
                    acc[i][j] = MFMA(a[i], breg[j][kk], acc[i][j]);
        }

        // stage NEXT tile into the other buffer (no barrier here; B2+B3 fence it)
        if (t + nblocks < ntiles) {
            stage(cur ^ 1);
            if (t + 2 * nblocks < ntiles) issue(t + 2 * nblocks);
        }

        // pass A: v = acc + b1 in place; per-row (s,ss) partials via DPP
#pragma unroll
        for (int i = 0; i < 2; ++i)
#pragma unroll
            for (int r = 0; r < 4; ++r) {
                float v0 = acc[i][0][r] + b1v[0];
                float v1 = acc[i][1][r] + b1v[1];
                float v2 = acc[i][2][r] + b1v[2];
                float v3 = acc[i][3][r] + b1v[3];
                acc[i][0][r] = v0; acc[i][1][r] = v1; acc[i][2][r] = v2; acc[i][3][r] = v3;
                float s  = (v0 + v1) + (v2 + v3);
                float ss = __builtin_fmaf(v0, v0, __builtin_fmaf(v1, v1,
                           __builtin_fmaf(v2, v2, v3 * v3)));
                s = rowsum16(s); ss = rowsum16(ss);
                if (l15 == 0) {
                    int row = 16 * i + quad * 4 + r;          // C/D: row = quad*4+reg
                    *(float2*)&sm.rstat[row * 8 + cw * 2] = make_float2(s, ss);
                }
            }
        __syncthreads();                             // B2: rstat ready + next-tile sA staged

#pragma unroll
        for (int i = 0; i < 2; ++i)
#pragma unroll
            for (int r = 0; r < 4; ++r) {
                int row = 16 * i + quad * 4 + r;
                const float4* st = (const float4*)&sm.rstat[row * 8];
                float4 q0 = st[0], q1 = st[1];
                float s  = (q0.x + q0.z) + (q1.x + q1.z);
                float ss = (q0.y + q0.w) + (q1.y + q1.w);
                float mean = s * (1.f / 256.f);
                float var  = __builtin_fmaf(ss, 1.f / 256.f, -mean * mean);
                float rstd = __builtin_amdgcn_rsqf(var + 1e-5f);
                float nm = -mean * rstd;
                float spp = 0.f;
#pragma unroll
                for (int j = 0; j < 4; ++j) {
                    float tt = __builtin_fmaf(acc[i][j][r], rstd, nm);
                    float xn = __builtin_fmaf(tt, gv[j], bev[j]);
                    spp = __builtin_fmaf(gelu_fast(xn), w2v[j], spp);
                }
                spp = rowsum16(spp);
                if (l15 == 0) sm.spL[row * 4 + cw] = spp;
            }
        __syncthreads();                             // B3: spL ready (fences rstat/sA reuse)

        if (tid < 32) {
            int e = t * 32 + tid;
            if (e < E) {
                const float4* sp = (const float4*)&sm.spL[tid * 4];
                float4 u0 = sp[0];
                out[e] = ((u0.x + u0.y) + (u0.z + u0.w)) + b2v;
            }
        }
        cur ^= 1;
    }
}

// ---------------------------------------------------------------------------
// MLP heads: out = gelu(LN(x@W1+b1)*g+be) @ W2 + b2.  4 waves, 64-row tiles.
// GEMM1: wave owns CPW1=N1/4 cols; GEMM2: wave owns 16*JT2=N2/4 cols (breg2 post-B3).
// ---------------------------------------------------------------------------
template<int K, int N1, int N2>
__device__ void mlp_role(SmemMlp<N1 + 8>& sm, const float* __restrict__ x,
                         const float* __restrict__ w1, const float* __restrict__ b1,
                         const float* __restrict__ g, const float* __restrict__ be,
                         const float* __restrict__ w2, const float* __restrict__ b2,
                         float* __restrict__ out, int Nrows, int bid, int nblocks) {
    constexpr int KP = K + 8, N1P = N1 + 8;
    constexpr int CPW1 = N1 / 4;           // cols per wave, GEMM1 (A:32, B:64)
    constexpr int JT1 = CPW1 / 16;         // A:2, B:4
    constexpr int KK1 = K / 32;            // 2
    constexpr int KK2 = N1 / 32;           // A:4, B:8
    constexpr int JT2 = N2 / 64;           // A:1, B:2

    const int tid = threadIdx.x;
    const int wave = tid >> 6, lane = tid & 63;
    const int l15 = lane & 15, quad = lane >> 4;

    short8 breg1[JT1][KK1];
#pragma unroll
    for (int j = 0; j < JT1; ++j)
#pragma unroll
        for (int kk = 0; kk < KK1; ++kk)
            breg1[j][kk] = load_bfrag(w1, kk * 32 + quad * 8, CPW1 * wave + 16 * j + l15, N1);

    float b1v[JT1], gv[JT1], bev[JT1];
#pragma unroll
    for (int j = 0; j < JT1; ++j) {
        int c = CPW1 * wave + 16 * j + l15;
        b1v[j] = b1[c]; gv[j] = g[c]; bev[j] = be[c];
    }
    float b2v[JT2];
#pragma unroll
    for (int j = 0; j < JT2; ++j) b2v[j] = b2[wave * 16 * JT2 + 16 * j + l15];

    const int ntiles = (Nrows + 63) >> 6;
    const int m0 = tid >> 2, pp = tid & 3;  // 4 threads per row, 16 floats each (K=64)

    for (int t = bid; t < ntiles; t += nblocks) {
        const int r0 = t << 6;
        __syncthreads();                       // B0: prev GEMM2 reads of sS done
        {
            int rowg = r0 + m0; if (rowg >= Nrows) rowg = Nrows - 1;
            const float4* src = (const float4*)(x + (long)rowg * K + pp * 16);
            unsigned short* dst = &sm.sS[m0 * KP + pp * 16];
#pragma unroll
            for (int u = 0; u < 4; ++u) {
                float4 f = src[u];
                ushort4 h; h.x = f2bf(f.x); h.y = f2bf(f.y); h.z = f2bf(f.z); h.w = f2bf(f.w);
                *(ushort4*)(dst + 4 * u) = h;
            }
        }
        __syncthreads();                       // B1: A ready

        f32x4 acc1[4][JT1];
#pragma unroll
        for (int i = 0; i < 4; ++i)
#pragma unroll
            for (int j = 0; j < JT1; ++j)
                acc1[i][j] = (f32x4){0.f, 0.f, 0.f, 0.f};

#pragma unroll
        for (int kk = 0; kk < KK1; ++kk) {
            short8 a[4];
#pragma unroll
            for (int i = 0; i < 4; ++i)
                a[i] = *(const short8*)&sm.sS[(16 * i + l15) * KP + kk * 32 + quad * 8];
#pragma unroll
            for (int i = 0; i < 4; ++i)
#pragma unroll
                for (int j = 0; j < JT1; ++j)
                    acc1[i][j] = MFMA(a[i], breg1[j][kk], acc1[i][j]);
        }

#pragma unroll
        for (int i = 0; i < 4; ++i)
#pragma unroll
            for (int r = 0; r < 4; ++r) {
                float s = 0.f, ss = 0.f;
#pragma unroll
                for (int j = 0; j < JT1; ++j) {
                    float v = acc1[i][j][r] + b1v[j];
                    acc1[i][j][r] = v;
                    s += v; ss = __builtin_fmaf(v, v, ss);
                }
                s = rowsum16(s); ss = rowsum16(ss);
                if (l15 == 0) {
                    int row = 16 * i + quad * 4 + r;
                    *(float2*)&sm.rstat[row * 8 + wave * 2] = make_float2(s, ss);
                }
            }
        __syncthreads();                       // B2: partials ready (GEMM1 sS reads done)

#pragma unroll
        for (int i = 0; i < 4; ++i)
#pragma unroll
            for (int r = 0; r < 4; ++r) {
                int row = 16 * i + quad * 4 + r;
                const float4* st = (const float4*)&sm.rstat[row * 8];
                float4 q0 = st[0], q1 = st[1];
                float s  = (q0.x + q0.z) + (q1.x + q1.z);
                float ss = (q0.y + q0.w) + (q1.y + q1.w);
                float mean = s * (1.f / (float)N1);
                float var  = __builtin_fmaf(ss, 1.f / (float)N1, -mean * mean);
                float rstd = __builtin_amdgcn_rsqf(var + 1e-5f);
                float nm = -mean * rstd;
#pragma unroll
                for (int j = 0; j < JT1; ++j) {
                    float tt = __builtin_fmaf(acc1[i][j][r], rstd, nm);
                    float xn = __builtin_fmaf(tt, gv[j], bev[j]);
                    sm.sS[row * N1P + CPW1 * wave + 16 * j + l15] = f2bf(gelu_fast(xn));
                }
            }
        __syncthreads();                       // B3: gelu(h) ready in A-layout

        // breg2 loaded here: acc1 is dead, registers reusable
        short8 breg2[JT2][KK2];
#pragma unroll
        for (int j = 0; j < JT2; ++j)
#pragma unroll
            for (int kk = 0; kk < KK2; ++kk)
                breg2[j][kk] = load_bfrag(w2, kk * 32 + quad * 8, wave * 16 * JT2 + 16 * j + l15, N2);

        f32x4 acc2[4][JT2];
#pragma unroll
        for (int i = 0; i < 4; ++i)
#pragma unroll
            for (int j = 0; j < JT2; ++j)
                acc2[i][j] = (f32x4){0.f, 0.f, 0.f, 0.f};

#pragma unroll
        for (int kk = 0; kk < KK2; ++kk) {
            short8 a[4];
#pragma unroll
            for (int i = 0; i < 4; ++i)
                a[i] = *(const short8*)&sm.sS[(16 * i + l15) * N1P + kk * 32 + quad * 8];
#pragma unroll
            for (int i = 0; i < 4; ++i)
#pragma unroll
                for (int j = 0; j < JT2; ++j)
                    acc2[i][j] = MFMA(a[i], breg2[j][kk], acc2[i][j]);
        }

#pragma unroll
        for (int i = 0; i < 4; ++i)
#pragma unroll
            for (int r = 0; r < 4; ++r) {
                int rowg = r0 + 16 * i + quad * 4 + r;
                if (rowg < Nrows) {
#pragma unroll
                    for (int j = 0; j < JT2; ++j)
                        out[(long)rowg * N2 + wave * 16 * JT2 + 16 * j + l15] = acc2[i][j][r] + b2v[j];
                }
            }
    }
}

// Merged kernel, 256 threads, 3 waves/EU (170-reg cap, 3 blocks/CU).
// MLP blocks (0..255) dispatch first, edge fills in behind.
__global__ __launch_bounds__(256, 3)
void fused_all(const float* __restrict__ x, const int* __restrict__ ei,
               const float* __restrict__ sp_w1, const float* __restrict__ sp_b1,
               const float* __restrict__ sp_g, const float* __restrict__ sp_be,
               const float* __restrict__ sp_w2, const float* __restrict__ sp_b2,
               const float* __restrict__ fr_w1, const float* __restrict__ fr_b1,
               const float* __restrict__ fr_g, const float* __restrict__ fr_be,
               const float* __restrict__ fr_w2, const float* __restrict__ fr_b2,
               const float* __restrict__ ph_w1, const float* __restrict__ ph_b1,
               const float* __restrict__ ph_g, const float* __restrict__ ph_be,
               const float* __restrict__ ph_w2, const float* __restrict__ ph_b2,
               float* __restrict__ out_sp, float* __restrict__ out_rec,
               float* __restrict__ out_proj, int N, int E) {
    __shared__ SmemU sm;
    const int b = blockIdx.x;
    if (b < 128) {
        mlp_role<64, 128, 64>(sm.a, x, fr_w1, fr_b1, fr_g, fr_be, fr_w2, fr_b2,
                              out_rec, N, b, 128);
    } else if (b < 256) {
        mlp_role<64, 256, 128>(sm.b, x, ph_w1, ph_b1, ph_g, ph_be, ph_w2, ph_b2,
                               out_proj, N, b - 128, 128);
    } else {
        edge_role(sm.e, x, ei, sp_w1, sp_b1, sp_g, sp_be, sp_w2, sp_b2,
                  out_sp, E, b - 256, 1024);
    }
}

extern "C" void kernel_launch(void* const* d_in, const int* in_sizes, int n_in,
                              void* d_out, int out_size, void* d_ws, size_t ws_size,
                              hipStream_t stream) {
    const float* x     = (const float*)d_in[0];
    const int*   ei    = (const int*)d_in[1];

    const int N = in_sizes[0] / 64;
    const int E = in_sizes[1] / 2;

    float* out_sp   = (float*)d_out;
    float* out_rec  = out_sp + E;
    float* out_proj = out_rec + (size_t)N * 64;

    fused_all<<<dim3(1280), dim3(256), 0, stream>>>(
        x, ei,
        (const float*)d_in[2],  (const float*)d_in[3],  (const float*)d_in[4],
        (const float*)d_in[5],  (const float*)d_in[6],  (const float*)d_in[7],
        (const float*)d_in[8],  (const float*)d_in[9],  (const float*)d_in[10],
        (const float*)d_in[11], (const float*)d_in[12], (const float*)d_in[13],
        (const float*)d_in[14], (const float*)d_in[15], (const float*)d_in[16],
        (const float*)d_in[17], (const float*)d_in[18], (const float*)d_in[19],
        out_sp, out_rec, out_proj, N, E);
}

// Round 7
// 305.272 us; speedup vs baseline: 2.5022x; 1.3317x over previous
//
#include <hip/hip_runtime.h>
#include <hip/hip_bf16.h>

typedef __attribute__((ext_vector_type(8))) short short8;   // 8 bf16 = 4 VGPRs (MFMA A/B frag)
typedef __attribute__((ext_vector_type(4))) float f32x4;    // MFMA C/D frag

#define MFMA(a, b, c) __builtin_amdgcn_mfma_f32_16x16x32_bf16((a), (b), (c), 0, 0, 0)

__device__ __forceinline__ unsigned short f2bf(float f) {
    unsigned int u = __float_as_uint(f);
    u += 0x7fffu + ((u >> 16) & 1u);          // round-to-nearest-even
    return (unsigned short)(u >> 16);
}

// 16-lane sum via DPP row_ror (VALU-only). Each 16-lane row gets its full sum.
template<int CTRL>
__device__ __forceinline__ float dpp_addf(float v) {
    int t = __builtin_amdgcn_update_dpp(0, __float_as_int(v), CTRL, 0xF, 0xF, true);
    return v + __int_as_float(t);
}
__device__ __forceinline__ float rowsum16(float v) {
    v = dpp_addf<0x121>(v);   // row_ror:1
    v = dpp_addf<0x122>(v);   // row_ror:2
    v = dpp_addf<0x124>(v);   // row_ror:4
    v = dpp_addf<0x128>(v);   // row_ror:8
    return v;
}

// gelu tanh-form: x*E/(E+1), E=exp(x*(1.59576912+0.07135533x^2)); |err| <~3e-4.
__device__ __forceinline__ float gelu_fast(float x) {
    x = __builtin_amdgcn_fmed3f(x, -8.0f, 8.0f);
    float a = x * __builtin_fmaf(x * x, 0.07135533f, 1.59576912f);
    float E = __expf(a);
    float r = __builtin_amdgcn_rcpf(E + 1.0f);
    return x * E * r;
}

// B fragment from row-major [K][ldn] fp32 weight: r[u] = W[k0+u][n].
__device__ __forceinline__ short8 load_bfrag(const float* __restrict__ w, int k0, int n, int ldn) {
    short8 r;
#pragma unroll
    for (int u = 0; u < 8; ++u)
        r[u] = (short)f2bf(w[(k0 + u) * ldn + n]);
    return r;
}

template<int N1P>
struct SmemMlp {
    unsigned short sS[64 * N1P];     // union: A [64][K+8] then gelu(h) [64][N1P]
    float rstat[64 * 8];
};

// ---------------------------------------------------------------------------
// MLP heads: out = gelu(LN(x@W1+b1)*g+be) @ W2 + b2.  4 waves, 64-row tiles.
// (validated structure from R6)
// ---------------------------------------------------------------------------
template<int K, int N1, int N2>
__device__ void mlp_role(SmemMlp<N1 + 8>& sm, const float* __restrict__ x,
                         const float* __restrict__ w1, const float* __restrict__ b1,
                         const float* __restrict__ g, const float* __restrict__ be,
                         const float* __restrict__ w2, const float* __restrict__ b2,
                         float* __restrict__ out, int Nrows, int bid, int nblocks) {
    constexpr int KP = K + 8, N1P = N1 + 8;
    constexpr int CPW1 = N1 / 4;
    constexpr int JT1 = CPW1 / 16;
    constexpr int KK1 = K / 32;
    constexpr int KK2 = N1 / 32;
    constexpr int JT2 = N2 / 64;

    const int tid = threadIdx.x;
    const int wave = tid >> 6, lane = tid & 63;
    const int l15 = lane & 15, quad = lane >> 4;

    short8 breg1[JT1][KK1];
#pragma unroll
    for (int j = 0; j < JT1; ++j)
#pragma unroll
        for (int kk = 0; kk < KK1; ++kk)
            breg1[j][kk] = load_bfrag(w1, kk * 32 + quad * 8, CPW1 * wave + 16 * j + l15, N1);

    float b1v[JT1], gv[JT1], bev[JT1];
#pragma unroll
    for (int j = 0; j < JT1; ++j) {
        int c = CPW1 * wave + 16 * j + l15;
        b1v[j] = b1[c]; gv[j] = g[c]; bev[j] = be[c];
    }
    float b2v[JT2];
#pragma unroll
    for (int j = 0; j < JT2; ++j) b2v[j] = b2[wave * 16 * JT2 + 16 * j + l15];

    const int ntiles = (Nrows + 63) >> 6;
    const int m0 = tid >> 2, pp = tid & 3;

    for (int t = bid; t < ntiles; t += nblocks) {
        const int r0 = t << 6;
        __syncthreads();                       // B0: prev GEMM2 reads of sS done
        {
            int rowg = r0 + m0; if (rowg >= Nrows) rowg = Nrows - 1;
            const float4* src = (const float4*)(x + (long)rowg * K + pp * 16);
            unsigned short* dst = &sm.sS[m0 * KP + pp * 16];
#pragma unroll
            for (int u = 0; u < 4; ++u) {
                float4 f = src[u];
                ushort4 h; h.x = f2bf(f.x); h.y = f2bf(f.y); h.z = f2bf(f.z); h.w = f2bf(f.w);
                *(ushort4*)(dst + 4 * u) = h;
            }
        }
        __syncthreads();                       // B1: A ready

        f32x4 acc1[4][JT1];
#pragma unroll
        for (int i = 0; i < 4; ++i)
#pragma unroll
            for (int j = 0; j < JT1; ++j)
                acc1[i][j] = (f32x4){0.f, 0.f, 0.f, 0.f};

#pragma unroll
        for (int kk = 0; kk < KK1; ++kk) {
            short8 a[4];
#pragma unroll
            for (int i = 0; i < 4; ++i)
                a[i] = *(const short8*)&sm.sS[(16 * i + l15) * KP + kk * 32 + quad * 8];
#pragma unroll
            for (int i = 0; i < 4; ++i)
#pragma unroll
                for (int j = 0; j < JT1; ++j)
                    acc1[i][j] = MFMA(a[i], breg1[j][kk], acc1[i][j]);
        }

#pragma unroll
        for (int i = 0; i < 4; ++i)
#pragma unroll
            for (int r = 0; r < 4; ++r) {
                float s = 0.f, ss = 0.f;
#pragma unroll
                for (int j = 0; j < JT1; ++j) {
                    float v = acc1[i][j][r] + b1v[j];
                    acc1[i][j][r] = v;
                    s += v; ss = __builtin_fmaf(v, v, ss);
                }
                s = rowsum16(s); ss = rowsum16(ss);
                if (l15 == 0) {
                    int row = 16 * i + quad * 4 + r;
                    *(float2*)&sm.rstat[row * 8 + wave * 2] = make_float2(s, ss);
                }
            }
        __syncthreads();                       // B2: partials ready

#pragma unroll
        for (int i = 0; i < 4; ++i)
#pragma unroll
            for (int r = 0; r < 4; ++r) {
                int row = 16 * i + quad * 4 + r;
                const float4* st = (const float4*)&sm.rstat[row * 8];
                float4 q0 = st[0], q1 = st[1];
                float s  = (q0.x + q0.z) + (q1.x + q1.z);
                float ss = (q0.y + q0.w) + (q1.y + q1.w);
                float mean = s * (1.f / (float)N1);
                float var  = __builtin_fmaf(ss, 1.f / (float)N1, -mean * mean);
                float rstd = __builtin_amdgcn_rsqf(var + 1e-5f);
                float nm = -mean * rstd;
#pragma unroll
                for (int j = 0; j < JT1; ++j) {
                    float tt = __builtin_fmaf(acc1[i][j][r], rstd, nm);
                    float xn = __builtin_fmaf(tt, gv[j], bev[j]);
                    sm.sS[row * N1P + CPW1 * wave + 16 * j + l15] = f2bf(gelu_fast(xn));
                }
            }
        __syncthreads();                       // B3: gelu(h) ready in A-layout

        short8 breg2[JT2][KK2];
#pragma unroll
        for (int j = 0; j < JT2; ++j)
#pragma unroll
            for (int kk = 0; kk < KK2; ++kk)
                breg2[j][kk] = load_bfrag(w2, kk * 32 + quad * 8, wave * 16 * JT2 + 16 * j + l15, N2);

        f32x4 acc2[4][JT2];
#pragma unroll
        for (int i = 0; i < 4; ++i)
#pragma unroll
            for (int j = 0; j < JT2; ++j)
                acc2[i][j] = (f32x4){0.f, 0.f, 0.f, 0.f};

#pragma unroll
        for (int kk = 0; kk < KK2; ++kk) {
            short8 a[4];
#pragma unroll
            for (int i = 0; i < 4; ++i)
                a[i] = *(const short8*)&sm.sS[(16 * i + l15) * N1P + kk * 32 + quad * 8];
#pragma unroll
            for (int i = 0; i < 4; ++i)
#pragma unroll
                for (int j = 0; j < JT2; ++j)
                    acc2[i][j] = MFMA(a[i], breg2[j][kk], acc2[i][j]);
        }

#pragma unroll
        for (int i = 0; i < 4; ++i)
#pragma unroll
            for (int r = 0; r < 4; ++r) {
                int rowg = r0 + 16 * i + quad * 4 + r;
                if (rowg < Nrows) {
#pragma unroll
                    for (int j = 0; j < JT2; ++j)
                        out[(long)rowg * N2 + wave * 16 * JT2 + 16 * j + l15] = acc2[i][j][r] + b2v[j];
                }
            }
    }
}

// ---------------------------------------------------------------------------
// P-projection: P = x @ W1half (+ b1 for the A-plane), stored bf16 [N][256].
// One 64-row x 256-col tile per block; 4 waves x 64 cols; K=64.
// ---------------------------------------------------------------------------
__device__ void proj_role(unsigned short* sX /*64*72*/, const float* __restrict__ x,
                          const float* __restrict__ w1, const float* __restrict__ b1,
                          unsigned short* __restrict__ P, int N, int tile, int isB) {
    constexpr int KP = 72;                     // 144B stride -> 2-way alias (free)
    const int tid = threadIdx.x;
    const int wave = tid >> 6, lane = tid & 63;
    const int l15 = lane & 15, quad = lane >> 4;

    short8 breg[4][2];
#pragma unroll
    for (int j = 0; j < 4; ++j)
#pragma unroll
        for (int kk = 0; kk < 2; ++kk)
            breg[j][kk] = load_bfrag(w1, isB * 64 + kk * 32 + quad * 8, wave * 64 + 16 * j + l15, 256);

    float b1v[4];
#pragma unroll
    for (int j = 0; j < 4; ++j)
        b1v[j] = isB ? 0.f : b1[wave * 64 + 16 * j + l15];

    const int r0 = tile * 64;
    {
        int m0 = tid >> 2, pp = tid & 3;       // 4 threads/row, 16 floats each
        int rowg = r0 + m0; if (rowg >= N) rowg = N - 1;
        const float4* src = (const float4*)(x + (long)rowg * 64 + pp * 16);
        unsigned short* dst = &sX[m0 * KP + pp * 16];
#pragma unroll
        for (int u = 0; u < 4; ++u) {
            float4 f = src[u];
            ushort4 h; h.x = f2bf(f.x); h.y = f2bf(f.y); h.z = f2bf(f.z); h.w = f2bf(f.w);
            *(ushort4*)(dst + 4 * u) = h;
        }
    }
    __syncthreads();

    f32x4 acc[4][4];
#pragma unroll
    for (int i = 0; i < 4; ++i)
#pragma unroll
        for (int j = 0; j < 4; ++j)
            acc[i][j] = (f32x4){0.f, 0.f, 0.f, 0.f};

#pragma unroll
    for (int kk = 0; kk < 2; ++kk) {
        short8 a[4];
#pragma unroll
        for (int i = 0; i < 4; ++i)
            a[i] = *(const short8*)&sX[(16 * i + l15) * KP + kk * 32 + quad * 8];
#pragma unroll
        for (int i = 0; i < 4; ++i)
#pragma unroll
            for (int j = 0; j < 4; ++j)
                acc[i][j] = MFMA(a[i], breg[j][kk], acc[i][j]);
    }

#pragma unroll
    for (int i = 0; i < 4; ++i)
#pragma unroll
        for (int r = 0; r < 4; ++r) {
            int rowg = r0 + 16 * i + quad * 4 + r;     // C/D: row = quad*4+reg
            if (rowg < N) {
#pragma unroll
                for (int j = 0; j < 4; ++j)
                    P[(long)rowg * 256 + wave * 64 + 16 * j + l15] = f2bf(acc[i][j][r] + b1v[j]);
            }
        }
}

union SmemPrep {
    SmemMlp<136> a;            // head A: N1=128
    SmemMlp<264> b;            // head B: N1=256 (35.8 KB, the max)
    unsigned short sX[64 * 72];
};

// kernel1: MLP heads (blocks 0..255) + P-projection (blocks 256..255+2*ntN)
__global__ __launch_bounds__(256)
void prep_kernel(const float* __restrict__ x,
                 const float* __restrict__ sp_w1, const float* __restrict__ sp_b1,
                 const float* __restrict__ fr_w1, const float* __restrict__ fr_b1,
                 const float* __restrict__ fr_g, const float* __restrict__ fr_be,
                 const float* __restrict__ fr_w2, const float* __restrict__ fr_b2,
                 const float* __restrict__ ph_w1, const float* __restrict__ ph_b1,
                 const float* __restrict__ ph_g, const float* __restrict__ ph_be,
                 const float* __restrict__ ph_w2, const float* __restrict__ ph_b2,
                 unsigned short* __restrict__ Pa, unsigned short* __restrict__ Pb,
                 float* __restrict__ out_rec, float* __restrict__ out_proj,
                 int N, int ntN) {
    __shared__ SmemPrep sm;
    const int b = blockIdx.x;
    if (b < 128) {
        mlp_role<64, 128, 64>(sm.a, x, fr_w1, fr_b1, fr_g, fr_be, fr_w2, fr_b2,
                              out_rec, N, b, 128);
    } else if (b < 256) {
        mlp_role<64, 256, 128>(sm.b, x, ph_w1, ph_b1, ph_g, ph_be, ph_w2, ph_b2,
                               out_proj, N, b - 128, 128);
    } else {
        int pb = b - 256;
        int isB = pb >= ntN;
        int tile = isB ? pb - ntN : pb;
        proj_role(sm.sX, x, sp_w1, sp_b1, isB ? Pb : Pa, N, tile, isB);
    }
}

// ---------------------------------------------------------------------------
// kernel2: edge stream. Per wave: 4 edges (one per 16-lane quad), 16 cols/lane.
// h = Pa[row] + Pb[col] (bf16 gather, fully coalesced 512B rows); LN via DPP
// rowsum16; gelu; dot w2; lane0-of-quad writes. No LDS, no barriers, no MFMA.
// ---------------------------------------------------------------------------
__global__ __launch_bounds__(256)
void edge_stream(const unsigned short* __restrict__ Pa, const unsigned short* __restrict__ Pb,
                 const int* __restrict__ ei,
                 const float* __restrict__ g, const float* __restrict__ be,
                 const float* __restrict__ w2, const float* __restrict__ b2,
                 float* __restrict__ out, int E) {
    const int tid = threadIdx.x;
    const int lane = tid & 63;
    const int quad = lane >> 4, l15 = lane & 15;

    // loop-invariant per-lane column params: cols l15*16 .. l15*16+15
    float gv[16], bev[16], w2v[16];
    {
        const float4* gp = (const float4*)(g + l15 * 16);
        const float4* bp = (const float4*)(be + l15 * 16);
        const float4* wp = (const float4*)(w2 + l15 * 16);
#pragma unroll
        for (int u = 0; u < 4; ++u) {
            float4 gq = gp[u], bq = bp[u], wq = wp[u];
            gv[4*u+0] = gq.x; gv[4*u+1] = gq.y; gv[4*u+2] = gq.z; gv[4*u+3] = gq.w;
            bev[4*u+0] = bq.x; bev[4*u+1] = bq.y; bev[4*u+2] = bq.z; bev[4*u+3] = bq.w;
            w2v[4*u+0] = wq.x; w2v[4*u+1] = wq.y; w2v[4*u+2] = wq.z; w2v[4*u+3] = wq.w;
        }
    }
    const float b2v = b2[0];

    const int wid = blockIdx.x * 4 + (tid >> 6);
    const int nw = gridDim.x * 4;

    for (long base = (long)wid * 4; base < E; base += (long)nw * 4) {
        long eL = base + quad;
        bool ok = eL < E;
        int e = ok ? (int)eL : E - 1;
        int ir = ei[e], ic = ei[E + e];

        const uint4* pa = (const uint4*)(Pa + (long)ir * 256 + l15 * 16);
        const uint4* pb = (const uint4*)(Pb + (long)ic * 256 + l15 * 16);
        uint4 A0 = pa[0], A1 = pa[1];
        uint4 B0 = pb[0], B1 = pb[1];

        unsigned int av[8] = {A0.x, A0.y, A0.z, A0.w, A1.x, A1.y, A1.z, A1.w};
        unsigned int bv[8] = {B0.x, B0.y, B0.z, B0.w, B1.x, B1.y, B1.z, B1.w};

        float h[16];
#pragma unroll
        for (int k = 0; k < 8; ++k) {
            float alo = __uint_as_float(av[k] << 16);
            float ahi = __uint_as_float(av[k] & 0xffff0000u);
            float blo = __uint_as_float(bv[k] << 16);
            float bhi = __uint_as_float(bv[k] & 0xffff0000u);
            h[2*k]   = alo + blo;
            h[2*k+1] = ahi + bhi;
        }

        float s = 0.f, ss = 0.f;
#pragma unroll
        for (int u = 0; u < 16; ++u) {
            s += h[u];
            ss = __builtin_fmaf(h[u], h[u], ss);
        }
        s = rowsum16(s); ss = rowsum16(ss);

        float mean = s * (1.f / 256.f);
        float var  = __builtin_fmaf(ss, 1.f / 256.f, -mean * mean);
        float rstd = __builtin_amdgcn_rsqf(var + 1e-5f);
        float nm = -mean * rstd;

        float spp = 0.f;
#pragma unroll
        for (int u = 0; u < 16; ++u) {
            float tt = __builtin_fmaf(h[u], rstd, nm);
            float xn = __builtin_fmaf(tt, gv[u], bev[u]);
            spp = __builtin_fmaf(gelu_fast(xn), w2v[u], spp);
        }
        spp = rowsum16(spp);
        if (l15 == 0 && ok) out[eL] = spp + b2v;
    }
}

// ======================= R6 fallback (ws too small) ==========================
struct SmemEdge {
    unsigned short sA[2][32 * 136];
    float rstat[32 * 8];
    float spL[32 * 4];
};
union SmemU {
    SmemEdge e;
    SmemMlp<136> a;
    SmemMlp<264> b;
};

__device__ void edge_role(SmemEdge& sm, const float* __restrict__ x, const int* __restrict__ ei,
                          const float* __restrict__ w1, const float* __restrict__ b1,
                          const float* __restrict__ g, const float* __restrict__ be,
                          const float* __restrict__ w2, const float* __restrict__ b2,
                          float* __restrict__ out, int E, int bid, int nblocks) {
    constexpr int KP = 136;
    const int tid = threadIdx.x;
    const int cw = tid >> 6, lane = tid & 63;
    const int l15 = lane & 15, quad = lane >> 4;

    short8 breg[4][4];
#pragma unroll
    for (int j = 0; j < 4; ++j)
#pragma unroll
        for (int kk = 0; kk < 4; ++kk)
            breg[j][kk] = load_bfrag(w1, kk * 32 + quad * 8, cw * 64 + 16 * j + l15, 256);

    float b1v[4], gv[4], bev[4], w2v[4];
#pragma unroll
    for (int j = 0; j < 4; ++j) {
        int c = cw * 64 + 16 * j + l15;
        b1v[j] = b1[c]; gv[j] = g[c]; bev[j] = be[c]; w2v[j] = w2[c];
    }
    const float b2v = b2[0];

    const int ntiles = (E + 31) >> 5;
    const int eLoc = tid >> 3, p = tid & 7;
    const int node = p >> 2, foff = (p & 3) * 16;

    float4 pf[4];
    auto issue = [&](int t) {
        int e = t * 32 + eLoc; if (e >= E) e = E - 1;
        int idx = ei[node * E + e];
        const float4* src = (const float4*)(x + (long)idx * 64 + foff);
#pragma unroll
        for (int u = 0; u < 4; ++u) pf[u] = src[u];
    };
    auto stage = [&](int buf) {
        unsigned short* dst = &sm.sA[buf][eLoc * KP + node * 64 + foff];
#pragma unroll
        for (int u = 0; u < 4; ++u) {
            ushort4 h;
            h.x = f2bf(pf[u].x); h.y = f2bf(pf[u].y);
            h.z = f2bf(pf[u].z); h.w = f2bf(pf[u].w);
            *(ushort4*)(dst + 4 * u) = h;
        }
    };

    int t = bid;
    if (t >= ntiles) return;
    issue(t); stage(0);
    if (t + nblocks < ntiles) issue(t + nblocks);
    __syncthreads();
    int cur = 0;

    for (; t < ntiles; t += nblocks) {
        f32x4 acc[2][4];
#pragma unroll
        for (int i = 0; i < 2; ++i)
#pragma unroll
            for (int j = 0; j < 4; ++j)
                acc[i][j] = (f32x4){0.f, 0.f, 0.f, 0.f};

#pragma unroll
        for (int kk = 0; kk < 4; ++kk) {
            short8 a[2];
#pragma unroll
            for (int i = 0; i < 2; ++i)
                a[i] = *(const short8*)&sm.sA[cur][(16 * i + l15) * KP + kk * 32 + quad * 8];
#pragma unroll
            for (int i = 0; i < 2; ++i)
#pragma unroll
                for (int j = 0; j < 4; ++j)
                    acc[i][j] = MFMA(a[i], breg[j][kk], acc[i][j]);
        }

        if (t + nblocks < ntiles) {
            stage(cur ^ 1);
            if (t + 2 * nblocks < ntiles) issue(t + 2 * nblocks);
        }

#pragma unroll
        for (int i = 0; i < 2; ++i)
#pragma unroll
            for (int r = 0; r < 4; ++r) {
                float v0 = acc[i][0][r] + b1v[0];
                float v1 = acc[i][1][r] + b1v[1];
                float v2 = acc[i][2][r] + b1v[2];
                float v3 = acc[i][3][r] + b1v[3];
                acc[i][0][r] = v0; acc[i][1][r] = v1; acc[i][2][r] = v2; acc[i][3][r] = v3;
                float s  = (v0 + v1) + (v2 + v3);
                float ss = __builtin_fmaf(v0, v0, __builtin_fmaf(v1, v1,
                           __builtin_fmaf(v2, v2, v3 * v3)));
                s = rowsum16(s); ss = rowsum16(ss);
                if (l15 == 0) {
                    int row = 16 * i + quad * 4 + r;
                    *(float2*)&sm.rstat[row * 8 + cw * 2] = make_float2(s, ss);
                }
            }
        __syncthreads();

#pragma unroll
        for (int i = 0; i < 2; ++i)
#pragma unroll
            for (int r = 0; r < 4; ++r) {
                int row = 16 * i + quad * 4 + r;
                const float4* st = (const float4*)&sm.rstat[row * 8];
                float4 q0 = st[0], q1 = st[1];
                float s  = (q0.x + q0.z) + (q1.x + q1.z);
                float ss = (q0.y + q0.w) + (q1.y + q1.w);
                float mean = s * (1.f / 256.f);
                float var  = __builtin_fmaf(ss, 1.f / 256.f, -mean * mean);
                float rstd = __builtin_amdgcn_rsqf(var + 1e-5f);
                float nm = -mean * rstd;
                float spp = 0.f;
#pragma unroll
                for (int j = 0; j < 4; ++j) {
                    float tt = __builtin_fmaf(acc[i][j][r], rstd, nm);
                    float xn = __builtin_fmaf(tt, gv[j], bev[j]);
                    spp = __builtin_fmaf(gelu_fast(xn), w2v[j], spp);
                }
                spp = rowsum16(spp);
                if (l15 == 0) sm.spL[row * 4 + cw] = spp;
            }
        __syncthreads();

        if (tid < 32) {
            int e = t * 32 + tid;
            if (e < E) {
                const float4* sp = (const float4*)&sm.spL[tid * 4];
                float4 u0 = sp[0];
                out[e] = ((u0.x + u0.y) + (u0.z + u0.w)) + b2v;
            }
        }
        cur ^= 1;
    }
}

__global__ __launch_bounds__(256, 3)
void fused_all(const float* __restrict__ x, const int* __restrict__ ei,
               const float* __restrict__ sp_w1, const float* __restrict__ sp_b1,
               const float* __restrict__ sp_g, const float* __restrict__ sp_be,
               const float* __restrict__ sp_w2, const float* __restrict__ sp_b2,
               const float* __restrict__ fr_w1, const float* __restrict__ fr_b1,
               const float* __restrict__ fr_g, const float* __restrict__ fr_be,
               const float* __restrict__ fr_w2, const float* __restrict__ fr_b2,
               const float* __restrict__ ph_w1, const float* __restrict__ ph_b1,
               const float* __restrict__ ph_g, const float* __restrict__ ph_be,
               const float* __restrict__ ph_w2, const float* __restrict__ ph_b2,
               float* __restrict__ out_sp, float* __restrict__ out_rec,
               float* __restrict__ out_proj, int N, int E) {
    __shared__ SmemU sm;
    const int b = blockIdx.x;
    if (b < 128) {
        mlp_role<64, 128, 64>(sm.a, x, fr_w1, fr_b1, fr_g, fr_be, fr_w2, fr_b2,
                              out_rec, N, b, 128);
    } else if (b < 256) {
        mlp_role<64, 256, 128>(sm.b, x, ph_w1, ph_b1, ph_g, ph_be, ph_w2, ph_b2,
                               out_proj, N, b - 128, 128);
    } else {
        edge_role(sm.e, x, ei, sp_w1, sp_b1, sp_g, sp_be, sp_w2, sp_b2,
                  out_sp, E, b - 256, 1024);
    }
}
// ===========================================================================

extern "C" void kernel_launch(void* const* d_in, const int* in_sizes, int n_in,
                              void* d_out, int out_size, void* d_ws, size_t ws_size,
                              hipStream_t stream) {
    const float* x     = (const float*)d_in[0];
    const int*   ei    = (const int*)d_in[1];
    const float* sp_w1 = (const float*)d_in[2];
    const float* sp_b1 = (const float*)d_in[3];
    const float* sp_g  = (const float*)d_in[4];
    const float* sp_be = (const float*)d_in[5];
    const float* sp_w2 = (const float*)d_in[6];
    const float* sp_b2 = (const float*)d_in[7];
    const float* fr_w1 = (const float*)d_in[8];
    const float* fr_b1 = (const float*)d_in[9];
    const float* fr_g  = (const float*)d_in[10];
    const float* fr_be = (const float*)d_in[11];
    const float* fr_w2 = (const float*)d_in[12];
    const float* fr_b2 = (const float*)d_in[13];
    const float* ph_w1 = (const float*)d_in[14];
    const float* ph_b1 = (const float*)d_in[15];
    const float* ph_g  = (const float*)d_in[16];
    const float* ph_be = (const float*)d_in[17];
    const float* ph_w2 = (const float*)d_in[18];
    const float* ph_b2 = (const float*)d_in[19];

    const int N = in_sizes[0] / 64;
    const int E = in_sizes[1] / 2;

    float* out_sp   = (float*)d_out;
    float* out_rec  = out_sp + E;
    float* out_proj = out_rec + (size_t)N * 64;

    const size_t needed = 2ull * (size_t)N * 256 * sizeof(unsigned short);
    if (ws_size >= needed) {
        unsigned short* Pa = (unsigned short*)d_ws;
        unsigned short* Pb = Pa + (size_t)N * 256;
        const int ntN = (N + 63) / 64;

        prep_kernel<<<dim3(256 + 2 * ntN), dim3(256), 0, stream>>>(
            x, sp_w1, sp_b1,
            fr_w1, fr_b1, fr_g, fr_be, fr_w2, fr_b2,
            ph_w1, ph_b1, ph_g, ph_be, ph_w2, ph_b2,
            Pa, Pb, out_rec, out_proj, N, ntN);

        edge_stream<<<dim3(2048), dim3(256), 0, stream>>>(
            Pa, Pb, ei, sp_g, sp_be, sp_w2, sp_b2, out_sp, E);
    } else {
        fused_all<<<dim3(1280), dim3(256), 0, stream>>>(
            x, ei, sp_w1, sp_b1, sp_g, sp_be, sp_w2, sp_b2,
            fr_w1, fr_b1, fr_g, fr_be, fr_w2, fr_b2,
            ph_w1, ph_b1, ph_g, ph_be, ph_w2, ph_b2,
            out_sp, out_rec, out_proj, N, E);
    }
}